// Round 2
// baseline (188.047 us; speedup 1.0000x reference)
//
#include <hip/hip_runtime.h>

// VectorQuantizer, fp16-split MFMA, split-K codebook sweep.
// scores = -2*E@C^T + ||c||^2; argmin_k; gather; mse losses.
//   e' = -2e = eh + el (fp16 RNE split), c' = 1024c = ch + cl (fp16 split)
//   -2*1024*dot(e,c) ~= (eh+el)@ch + eh@cl   (drop el@cl, err ~1e-8)
//   score = acc * 2^-10 + ||c||^2
// Grid 1024 = 512 row-blocks x 2 codebook halves; each block: 128 rows, 16 tiles.
// E rows live in VGPR frags; codebook tiles stream via global_load_lds (dbuf).
// Half-blocks write packed (best,second)+||e||^2 into the quantized out region
// as scratch; vq_merge merges halves, writes idx, flags, loss, and gathers.
// Rows whose top-2 gap < MARGIN get an exact fp32 rescan (vq_fix).
// Output: [0,N) idx as float | [N,N+N*D) quantized | +0,1,2 = vq,embed,commit.

#define NROWS 65536
#define KCB   1024
#define DIM   128
#define DV    32
#define MSE_DENOM 8388608.0f
#define MARGIN 2.0e-5f
#define FLAGCAP 16384
#define CSCALE   1024.0f
#define CDESCALE 0.0009765625f

// ws byte layout
#define WS_CNORM_F 256      // float index: cnorm[1024] at byte 1024
#define WS_LIST_B  8192     // 16384 ints
#define WS_PH_B    73728    // 262144 B packed codebook hi frags (fp16)
#define WS_PL_B    335872   // 262144 B packed codebook lo frags (fp16)
#define WS_NEEDED  598016

typedef __attribute__((ext_vector_type(16))) float float16v;
typedef _Float16 half8 __attribute__((ext_vector_type(8)));
union U4H8 { uint4 u; half8 h; };
union F4A  { float4 v; float f[4]; };
union HU   { _Float16 f; unsigned short u; };

__device__ __forceinline__ unsigned umn(unsigned a, unsigned b) { return a < b ? a : b; }
__device__ __forceinline__ unsigned umx(unsigned a, unsigned b) { return a > b ? a : b; }
__device__ __forceinline__ float unmap_score(unsigned up) {
  return (up & 0x80000000u) ? __uint_as_float(up ^ 0x80000000u) : __uint_as_float(~up);
}
__device__ __forceinline__ void split2h(float y, unsigned& hb, unsigned& lb) {
  HU h, l;
  h.f = (_Float16)y;                 // RNE
  l.f = (_Float16)(y - (float)h.f);
  hb = h.u; lb = l.u;
}
__device__ __forceinline__ void gload16(const void* g, void* s) {
  __builtin_amdgcn_global_load_lds((const __attribute__((address_space(1))) unsigned int*)g,
                                   (__attribute__((address_space(3))) unsigned int*)s,
                                   16, 0, 0);
}

// ---------- prep0: cnorm + zero loss/nflag ----------
__global__ __launch_bounds__(256) void vq_prep0(const float* __restrict__ C,
                                                float* __restrict__ wsf) {
  int k = blockIdx.x * 256 + threadIdx.x;   // grid 4x256 == 1024
  if (k == 0) { wsf[0] = 0.0f; ((unsigned*)wsf)[1] = 0u; }
  const float4* c4 = (const float4*)C + (size_t)k * DV;
  float s = 0.f;
#pragma unroll 8
  for (int i = 0; i < DV; ++i) {
    float4 v = c4[i];
    s = fmaf(v.x, v.x, s); s = fmaf(v.y, v.y, s);
    s = fmaf(v.z, v.z, s); s = fmaf(v.w, v.w, s);
  }
  wsf[WS_CNORM_F + k] = s;
}

// ---------- pack codebook into frag-linear hi/lo fp16 of (1024*c) ----------
// slot g in [0,16384): mt=g>>9, s=(g>>6)&7, l=g&63
// value j: C[mt*32+(l&31)][s*16+(l>>5)*8+j]
__global__ __launch_bounds__(256) void vq_pack(const float* __restrict__ C,
                                               uint4* __restrict__ PH,
                                               uint4* __restrict__ PL) {
  int g = blockIdx.x * 256 + threadIdx.x;   // grid 64x256
  int mt = g >> 9, s = (g >> 6) & 7, l = g & 63;
  int cw = mt * 32 + (l & 31);
  int k0 = s * 16 + (l >> 5) * 8;
  const float* src = C + (size_t)cw * DIM + k0;
  float4 x0 = *(const float4*)src;
  float4 x1 = *(const float4*)(src + 4);
  unsigned h[8], lo[8];
  split2h(CSCALE * x0.x, h[0], lo[0]); split2h(CSCALE * x0.y, h[1], lo[1]);
  split2h(CSCALE * x0.z, h[2], lo[2]); split2h(CSCALE * x0.w, h[3], lo[3]);
  split2h(CSCALE * x1.x, h[4], lo[4]); split2h(CSCALE * x1.y, h[5], lo[5]);
  split2h(CSCALE * x1.z, h[6], lo[6]); split2h(CSCALE * x1.w, h[7], lo[7]);
  PH[g] = make_uint4(h[0] | (h[1] << 16), h[2] | (h[3] << 16),
                     h[4] | (h[5] << 16), h[6] | (h[7] << 16));
  PL[g] = make_uint4(lo[0] | (lo[1] << 16), lo[2] | (lo[3] << 16),
                     lo[4] | (lo[5] << 16), lo[6] | (lo[7] << 16));
}

// ---------- main: split-K MFMA sweep, partials to out-region scratch ----------
__global__ __launch_bounds__(256, 4) void vq_main4(const float* __restrict__ E,
                                                   float* __restrict__ wsf,
                                                   float* __restrict__ out) {
  __shared__ uint4 SH[2][512];               // 8KB per buf: one 32-cw tile, hi
  __shared__ uint4 SL[2][512];               // lo
  __shared__ __align__(16) float CN[512];    // this half's cnorms

  const int tid    = threadIdx.x;
  const int w      = tid >> 6;               // wave 0..3
  const int l      = tid & 63;
  const int half   = l >> 5;
  const int rr     = l & 31;
  const int rowblk = blockIdx.x >> 1;
  const int cbhalf = blockIdx.x & 1;
  const int row0   = rowblk * 128;
  const int tgbase = cbhalf * 16;

  const uint4* PHg = (const uint4*)((const char*)wsf + WS_PH_B);
  const uint4* PLg = (const uint4*)((const char*)wsf + WS_PL_B);

  // ---- issue async stage of first tile + CN (overlaps E load/split below) ----
  {
    const uint4* sh = PHg + (size_t)tgbase * 512 + tid;
    const uint4* sl = PLg + (size_t)tgbase * 512 + tid;
    gload16(sh,       &SH[0][0] + tid);
    gload16(sh + 256, &SH[0][0] + tid + 256);
    gload16(sl,       &SL[0][0] + tid);
    gload16(sl + 256, &SL[0][0] + tid + 256);
    if (tid < 128)
      gload16(((const uint4*)(wsf + WS_CNORM_F + (cbhalf << 9))) + tid, ((uint4*)CN) + tid);
  }

  // ---- load this wave's 32 rows into register B-frags, fp16 hi/lo split ----
  // lane (rr,half) covers dims {s*16 + half*8 .. +7} for s=0..7  (64 floats)
  half8 beh[8], bel[8];
  float s2 = 0.f;
  const float* erow = E + (size_t)(row0 + w * 32 + rr) * DIM + half * 8;
#pragma unroll
  for (int s = 0; s < 8; ++s) {
    float4 x0 = *(const float4*)(erow + s * 16);
    float4 x1 = *(const float4*)(erow + s * 16 + 4);
    float v[8] = {x0.x, x0.y, x0.z, x0.w, x1.x, x1.y, x1.z, x1.w};
#pragma unroll
    for (int j = 0; j < 8; ++j) {
      float y = v[j];
      s2 = fmaf(y, y, s2);
      float t = -2.f * y;
      _Float16 hh = (_Float16)t;
      beh[s][j] = hh;
      bel[s][j] = (_Float16)(t - (float)hh);
    }
  }

  asm volatile("s_waitcnt vmcnt(0)" ::: "memory");
  __syncthreads();

  unsigned best = 0xFFFFFFFFu, second = 0xFFFFFFFFu;

  for (int t = 0; t < 16; ++t) {
    const int buf = t & 1;
    const int tg  = tgbase + t;
    // stage next tile (async, lands before next round's barrier)
    if (t < 15) {
      const uint4* sh = PHg + (size_t)(tg + 1) * 512 + tid;
      const uint4* sl = PLg + (size_t)(tg + 1) * 512 + tid;
      uint4* dh = &SH[buf ^ 1][0];
      uint4* dl = &SL[buf ^ 1][0];
      gload16(sh,       dh + tid);
      gload16(sh + 256, dh + tid + 256);
      gload16(sl,       dl + tid);
      gload16(sl + 256, dl + tid + 256);
    }

    float16v acc0 = {0,0,0,0,0,0,0,0,0,0,0,0,0,0,0,0};
    float16v acc1 = {0,0,0,0,0,0,0,0,0,0,0,0,0,0,0,0};
#pragma unroll
    for (int s = 0; s < 8; s += 2) {
      U4H8 h0, l0, h1, l1;
      h0.u = SH[buf][s * 64 + l];       l0.u = SL[buf][s * 64 + l];
      h1.u = SH[buf][(s + 1) * 64 + l]; l1.u = SL[buf][(s + 1) * 64 + l];
      acc0 = __builtin_amdgcn_mfma_f32_32x32x16_f16(h0.h, beh[s],     acc0, 0, 0, 0);
      acc1 = __builtin_amdgcn_mfma_f32_32x32x16_f16(h1.h, beh[s + 1], acc1, 0, 0, 0);
      acc0 = __builtin_amdgcn_mfma_f32_32x32x16_f16(l0.h, beh[s],     acc0, 0, 0, 0);
      acc1 = __builtin_amdgcn_mfma_f32_32x32x16_f16(l1.h, beh[s + 1], acc1, 0, 0, 0);
      acc0 = __builtin_amdgcn_mfma_f32_32x32x16_f16(h0.h, bel[s],     acc0, 0, 0, 0);
      acc1 = __builtin_amdgcn_mfma_f32_32x32x16_f16(h1.h, bel[s + 1], acc1, 0, 0, 0);
    }

    // fold 16 scores for this tile (lane's row = rr; cw = tg*32 + half*4 + q*8 + i)
    const unsigned cwb = (unsigned)(tg * 32 + half * 4);
#pragma unroll
    for (int q = 0; q < 4; ++q) {
      F4A a; a.v = *(const float4*)&CN[t * 32 + q * 8 + half * 4];
#pragma unroll
      for (int i = 0; i < 4; ++i) {
        float sc = fmaf(acc0[q * 4 + i] + acc1[q * 4 + i], CDESCALE, a.f[i]);
        unsigned u = __float_as_uint(sc);
        u ^= ((unsigned)(((int)u) >> 31)) | 0x80000000u;
        u = (u & 0xFFFFFC00u) | (cwb + (unsigned)(q * 8 + i));
        unsigned nb = umn(best, u);
        second = umn(second, umx(best, u));
        best = nb;
      }
    }

    asm volatile("s_waitcnt vmcnt(0)" ::: "memory");
    __syncthreads();
  }

  // ---- merge halves (lane l <-> l+32 hold same row, disjoint cw subsets) ----
  unsigned ob = (unsigned)__shfl_xor((int)best, 32, 64);
  unsigned os = (unsigned)__shfl_xor((int)second, 32, 64);
  unsigned ns = umn(umn(second, os), umx(best, ob));
  unsigned nb = umn(best, ob);
  float en = s2 + __shfl_xor(s2, 32, 64);

  if (half == 0) {
    const int R = row0 + w * 32 + rr;
    float* tmp = out + NROWS + (size_t)R * DIM;   // scratch in quantized region
    ((unsigned*)tmp)[cbhalf * 2 + 0] = nb;
    ((unsigned*)tmp)[cbhalf * 2 + 1] = ns;
    if (cbhalf == 0) tmp[4] = en;
  }
}

// ---------- merge halves, idx/flag/loss, gather quantized ----------
__global__ __launch_bounds__(256) void vq_merge(const float* __restrict__ C,
                                                float* __restrict__ wsf,
                                                float* __restrict__ out) {
  __shared__ int BI[256];
  const int tid  = threadIdx.x;
  const int row0 = blockIdx.x * 256;
  const int R    = row0 + tid;

  const float* tmp = out + NROWS + (size_t)R * DIM;
  unsigned bA = ((const unsigned*)tmp)[0], sA = ((const unsigned*)tmp)[1];
  unsigned bB = ((const unsigned*)tmp)[2], sB = ((const unsigned*)tmp)[3];
  float en = tmp[4];

  unsigned b = umn(bA, bB);
  unsigned s = umn(umn(sA, sB), umx(bA, bB));
  int   bi = (int)(b & 1023u);
  float bv = unmap_score(b & 0xFFFFFC00u);
  float sv = unmap_score(s & 0xFFFFFC00u);

  out[R] = (float)bi;
  BI[tid] = bi;
  if (sv - bv < MARGIN) {
    unsigned idx = atomicAdd((unsigned*)wsf + 1, 1u);
    if (idx < FLAGCAP) ((int*)((char*)wsf + WS_LIST_B))[idx] = R;
  }
  float term = en + bv;
#pragma unroll
  for (int off = 32; off > 0; off >>= 1) term += __shfl_down(term, off);
  if ((tid & 63) == 0) atomicAdd(wsf, term);
  __syncthreads();

  const float4* C4   = (const float4*)C;
  float4*       out4 = (float4*)out;
#pragma unroll
  for (int it = 0; it < 32; ++it) {
    int flat = it * 256 + tid;
    int r = flat >> 5, d4 = flat & 31;
    out4[(NROWS / 4) + (size_t)(row0 + r) * DV + d4] = C4[(size_t)BI[r] * DV + d4];
  }
}

// ---------- exact fp32 rescan of flagged rows (2 rows per sweep) ----------
__global__ __launch_bounds__(256) void vq_fix(const float* __restrict__ E,
                                              const float* __restrict__ C,
                                              float* __restrict__ wsf,
                                              float* __restrict__ out) {
  __shared__ float4 eL0[32], eL1[32];
  __shared__ float  sv0[256], sv1[256];
  __shared__ int    si0[256], si1[256];
  __shared__ int    RESi[2];
  const int tid = threadIdx.x;
  const int* list = (const int*)((const char*)wsf + WS_LIST_B);
  int nf = (int)((const unsigned*)wsf)[1];
  if (nf > FLAGCAP) nf = FLAGCAP;
  const float4* E4 = (const float4*)E;
  const float4* C4 = (const float4*)C;
  const float*  cn = wsf + WS_CNORM_F;
  float4* out4 = (float4*)out;

  for (int pair = blockIdx.x; pair * 2 < nf; pair += gridDim.x) {
    const int r0 = list[pair * 2];
    const int r1 = (pair * 2 + 1 < nf) ? list[pair * 2 + 1] : r0;
    if (tid < 32) eL0[tid] = E4[(size_t)r0 * DV + tid];
    else if (tid < 64) eL1[tid - 32] = E4[(size_t)r1 * DV + (tid - 32)];
    __syncthreads();
    float bv0 = 3.0e38f, bv1 = 3.0e38f; int bi0 = 0, bi1 = 0;
#pragma unroll
    for (int j = 0; j < 4; ++j) {
      int k = j * 256 + tid;
      float d0 = 0.f, d1 = 0.f;
#pragma unroll 8
      for (int d4 = 0; d4 < 32; ++d4) {
        float4 c = C4[(size_t)k * DV + d4];
        float4 e0 = eL0[d4], e1 = eL1[d4];
        d0 = fmaf(c.x, e0.x, d0); d0 = fmaf(c.y, e0.y, d0);
        d0 = fmaf(c.z, e0.z, d0); d0 = fmaf(c.w, e0.w, d0);
        d1 = fmaf(c.x, e1.x, d1); d1 = fmaf(c.y, e1.y, d1);
        d1 = fmaf(c.z, e1.z, d1); d1 = fmaf(c.w, e1.w, d1);
      }
      float s0 = fmaf(-2.f, d0, cn[k]);
      float s1 = fmaf(-2.f, d1, cn[k]);
      if (s0 < bv0 || (s0 == bv0 && k < bi0)) { bv0 = s0; bi0 = k; }
      if (s1 < bv1 || (s1 == bv1 && k < bi1)) { bv1 = s1; bi1 = k; }
    }
    sv0[tid] = bv0; si0[tid] = bi0; sv1[tid] = bv1; si1[tid] = bi1;
    __syncthreads();
    if (tid < 64) {
      float v0 = sv0[tid]; int i0 = si0[tid];
      float v1 = sv1[tid]; int i1 = si1[tid];
#pragma unroll
      for (int q = 1; q < 4; ++q) {
        float w0 = sv0[tid + q * 64]; int j0 = si0[tid + q * 64];
        float w1 = sv1[tid + q * 64]; int j1 = si1[tid + q * 64];
        if (w0 < v0 || (w0 == v0 && j0 < i0)) { v0 = w0; i0 = j0; }
        if (w1 < v1 || (w1 == v1 && j1 < i1)) { v1 = w1; i1 = j1; }
      }
#pragma unroll
      for (int off = 32; off > 0; off >>= 1) {
        float w0 = __shfl_down(v0, off); int j0 = __shfl_down(i0, off);
        float w1 = __shfl_down(v1, off); int j1 = __shfl_down(i1, off);
        if (w0 < v0 || (w0 == v0 && j0 < i0)) { v0 = w0; i0 = j0; }
        if (w1 < v1 || (w1 == v1 && j1 < i1)) { v1 = w1; i1 = j1; }
      }
      if (tid == 0) {
        RESi[0] = i0; RESi[1] = i1;
        out[r0] = (float)i0; out[r1] = (float)i1;
      }
    }
    __syncthreads();
    if (tid < 32) out4[(NROWS / 4) + (size_t)r0 * DV + tid] = C4[(size_t)RESi[0] * DV + tid];
    else if (tid < 64) out4[(NROWS / 4) + (size_t)r1 * DV + (tid - 32)] = C4[(size_t)RESi[1] * DV + (tid - 32)];
    __syncthreads();
  }
}

// ---------- final scalars ----------
__global__ void vq_final(const float* __restrict__ wsf, float* __restrict__ out) {
  if (threadIdx.x == 0 && blockIdx.x == 0) {
    float mse = wsf[0] / MSE_DENOM;
    out[NROWS + NROWS * DIM + 0] = 1.25f * mse;
    out[NROWS + NROWS * DIM + 1] = mse;
    out[NROWS + NROWS * DIM + 2] = mse;
  }
}

// ================= fallback (round-1 fp32 path, used if ws too small) ==========
__global__ __launch_bounds__(256) void vq_prep_fb(const float* __restrict__ C,
                                                  float* __restrict__ ws) {
  int k = blockIdx.x * 256 + threadIdx.x;
  if (k == 0) ws[0] = 0.0f;
  const float4* c4 = (const float4*)C + (size_t)k * DV;
  float s = 0.f;
#pragma unroll 8
  for (int i = 0; i < DV; ++i) {
    float4 v = c4[i];
    s = fmaf(v.x, v.x, s); s = fmaf(v.y, v.y, s);
    s = fmaf(v.z, v.z, s); s = fmaf(v.w, v.w, s);
  }
  ws[64 + k] = s;
}

__global__ __launch_bounds__(256) void vq_main_fb(const float* __restrict__ E,
                                                  const float* __restrict__ C,
                                                  const float* __restrict__ cnorm,
                                                  float* __restrict__ out,
                                                  float* __restrict__ lossacc) {
  __shared__ float smem[16384];
  float4* EsV = (float4*)smem;
  float4* CsV = (float4*)(smem + 8192);
  const int tid  = threadIdx.x;
  const int row0 = blockIdx.x * 64;
#pragma unroll
  for (int i = 0; i < 8; ++i) {
    int flat = i * 256 + tid;
    int r = flat >> 5, d4 = flat & 31;
    EsV[r * 32 + (d4 ^ (r & 31))] = ((const float4*)E)[(size_t)(row0 + r) * DV + d4];
  }
  const int tx = tid & 15, ty = tid >> 4;
  int rbase[4], rmask[4];
#pragma unroll
  for (int i = 0; i < 4; ++i) { int r = i * 16 + ty; rbase[i] = r * 32; rmask[i] = r & 31; }
  float bestv[4]; int besti[4];
#pragma unroll
  for (int i = 0; i < 4; ++i) { bestv[i] = 3.0e38f; besti[i] = 0; }
  for (int ch = 0; ch < 16; ++ch) {
    const int k0 = ch * 64;
    __syncthreads();
#pragma unroll
    for (int i = 0; i < 8; ++i) {
      int flat = i * 256 + tid;
      int k = flat >> 5, d4 = flat & 31;
      CsV[k * 32 + (d4 ^ (k & 31))] = ((const float4*)C)[(size_t)(k0 + k) * DV + d4];
    }
    __syncthreads();
    float acc[4][4] = {};
#pragma unroll 8
    for (int d4 = 0; d4 < DV; ++d4) {
      float4 a[4], b[4];
#pragma unroll
      for (int i = 0; i < 4; ++i) a[i] = EsV[rbase[i] + (d4 ^ rmask[i])];
#pragma unroll
      for (int j = 0; j < 4; ++j) { int k = j * 16 + tx; b[j] = CsV[k * 32 + (d4 ^ (k & 31))]; }
#pragma unroll
      for (int i = 0; i < 4; ++i)
#pragma unroll
        for (int j = 0; j < 4; ++j) {
          acc[i][j] = fmaf(a[i].x, b[j].x, acc[i][j]);
          acc[i][j] = fmaf(a[i].y, b[j].y, acc[i][j]);
          acc[i][j] = fmaf(a[i].z, b[j].z, acc[i][j]);
          acc[i][j] = fmaf(a[i].w, b[j].w, acc[i][j]);
        }
    }
#pragma unroll
    for (int j = 0; j < 4; ++j) {
      int kg = k0 + j * 16 + tx;
      float cnv = cnorm[kg];
#pragma unroll
      for (int i = 0; i < 4; ++i) {
        float s = fmaf(-2.0f, acc[i][j], cnv);
        if (s < bestv[i] || (s == bestv[i] && kg < besti[i])) { bestv[i] = s; besti[i] = kg; }
      }
    }
  }
  float* Rv = smem + 8192;
  int*   Ri = (int*)(smem + 9216);
  int*   BIf = (int*)(smem + 10240);
  __syncthreads();
#pragma unroll
  for (int i = 0; i < 4; ++i) {
    int r = i * 16 + ty;
    Rv[r * 16 + tx] = bestv[i];
    Ri[r * 16 + tx] = besti[i];
  }
  __syncthreads();
  if (tid < 64) {
    const int r = tid;
    float bv = Rv[r * 16]; int bi = Ri[r * 16];
#pragma unroll
    for (int t = 1; t < 16; ++t) {
      float v = Rv[r * 16 + t]; int ii = Ri[r * 16 + t];
      if (v < bv || (v == bv && ii < bi)) { bv = v; bi = ii; }
    }
    float en = 0.f;
#pragma unroll 8
    for (int d4 = 0; d4 < DV; ++d4) {
      float4 v = EsV[r * 32 + (d4 ^ (r & 31))];
      en = fmaf(v.x, v.x, en); en = fmaf(v.y, v.y, en);
      en = fmaf(v.z, v.z, en); en = fmaf(v.w, v.w, en);
    }
    out[row0 + r] = (float)bi;
    BIf[r] = bi;
    float blocksum = en + bv;
#pragma unroll
    for (int off = 32; off > 0; off >>= 1) blocksum += __shfl_down(blocksum, off);
    if (tid == 0) atomicAdd(lossacc, blocksum);
  }
  __syncthreads();
  const float4* C4   = (const float4*)C;
  float4*       out4 = (float4*)out;
  for (int flat = tid; flat < 64 * DV; flat += 256) {
    int r = flat >> 5, d4 = flat & 31;
    out4[(NROWS / 4) + (size_t)(row0 + r) * DV + d4] = C4[(size_t)BIf[r] * DV + d4];
  }
}

__global__ void vq_final_fb(const float* __restrict__ ws, float* __restrict__ out) {
  if (threadIdx.x == 0 && blockIdx.x == 0) {
    float mse = ws[0] / MSE_DENOM;
    out[NROWS + NROWS * DIM + 0] = 1.25f * mse;
    out[NROWS + NROWS * DIM + 1] = mse;
    out[NROWS + NROWS * DIM + 2] = mse;
  }
}

extern "C" void kernel_launch(void* const* d_in, const int* in_sizes, int n_in,
                              void* d_out, int out_size, void* d_ws, size_t ws_size,
                              hipStream_t stream) {
  const float* E = (const float*)d_in[0];
  const float* C = (const float*)d_in[1];
  float* out = (float*)d_out;
  float* wsf = (float*)d_ws;

  if (ws_size >= (size_t)WS_NEEDED) {
    uint4* PH = (uint4*)((char*)d_ws + WS_PH_B);
    uint4* PL = (uint4*)((char*)d_ws + WS_PL_B);
    vq_prep0<<<4, 256, 0, stream>>>(C, wsf);
    vq_pack<<<64, 256, 0, stream>>>(C, PH, PL);
    vq_main4<<<NROWS / 128 * 2, 256, 0, stream>>>(E, wsf, out);
    vq_merge<<<NROWS / 256, 256, 0, stream>>>(C, wsf, out);
    vq_fix<<<512, 256, 0, stream>>>(E, C, wsf, out);
    vq_final<<<1, 64, 0, stream>>>(wsf, out);
  } else {
    vq_prep_fb<<<4, 256, 0, stream>>>(C, wsf);
    vq_main_fb<<<NROWS / 64, 256, 0, stream>>>(E, C, wsf + 64, out, wsf);
    vq_final_fb<<<1, 64, 0, stream>>>(wsf, out);
  }
}

// Round 3
// 167.000 us; speedup vs baseline: 1.1260x; 1.1260x over previous
//
#include <hip/hip_runtime.h>

// VectorQuantizer, 2-term fp16 MFMA, register-resident E / LDS-streamed codebook.
// scores = -2*E@C^T + ||c||^2; argmin_k; gather; mse losses.
//   e' = -2e = eh + el (fp16 RNE split, register side)
//   c' = 1024c ~= ch (single fp16; dropped e'@cl err sigma ~2e-6 descaled)
//   -2*1024*dot(e,c) ~= eh@ch + el@ch ; score = acc * 2^-10 + ||c||^2
// Block = 128 threads (2 waves) x 64 rows; grid 1024 -> 4 blocks/CU.
// Codebook tiles (32 cw = 8KB) stream via global_load_lds, dbuf'd, staged one
// tile ahead. Fold of tile t-1 runs during tile t's MFMAs (deferred fold).
// Rows whose top-2 gap < MARGIN get an exact fp32 rescan (vq_fix).
// Output: [0,N) idx as float | [N,N+N*D) quantized | +0,1,2 = vq,embed,commit.

#define NROWS 65536
#define KCB   1024
#define DIM   128
#define DV    32
#define MSE_DENOM 8388608.0f
#define MARGIN 2.0e-5f
#define FLAGCAP 16384
#define CSCALE   1024.0f
#define CDESCALE 0.0009765625f

// ws byte layout
#define WS_CNORM_F 256      // float index: cnorm[1024] at byte 1024
#define WS_LIST_B  8192     // 16384 ints
#define WS_PH_B    73728    // 262144 B packed codebook hi frags (fp16)
#define WS_NEEDED  335872

typedef __attribute__((ext_vector_type(16))) float float16v;
typedef _Float16 half8 __attribute__((ext_vector_type(8)));
union U4H8 { uint4 u; half8 h; };
union F4A  { float4 v; float f[4]; };
union HU   { _Float16 f; unsigned short u; };

__device__ __forceinline__ unsigned umn(unsigned a, unsigned b) { return a < b ? a : b; }
__device__ __forceinline__ unsigned umx(unsigned a, unsigned b) { return a > b ? a : b; }
__device__ __forceinline__ float unmap_score(unsigned up) {
  return (up & 0x80000000u) ? __uint_as_float(up ^ 0x80000000u) : __uint_as_float(~up);
}
__device__ __forceinline__ void gload16(const void* g, void* s) {
  __builtin_amdgcn_global_load_lds((const __attribute__((address_space(1))) unsigned int*)g,
                                   (__attribute__((address_space(3))) unsigned int*)s,
                                   16, 0, 0);
}

// ---------- prep0: cnorm + zero loss/nflag ----------
__global__ __launch_bounds__(256) void vq_prep0(const float* __restrict__ C,
                                                float* __restrict__ wsf) {
  int k = blockIdx.x * 256 + threadIdx.x;   // grid 4x256 == 1024
  if (k == 0) { wsf[0] = 0.0f; ((unsigned*)wsf)[1] = 0u; }
  const float4* c4 = (const float4*)C + (size_t)k * DV;
  float s = 0.f;
#pragma unroll 8
  for (int i = 0; i < DV; ++i) {
    float4 v = c4[i];
    s = fmaf(v.x, v.x, s); s = fmaf(v.y, v.y, s);
    s = fmaf(v.z, v.z, s); s = fmaf(v.w, v.w, s);
  }
  wsf[WS_CNORM_F + k] = s;
}

// ---------- pack codebook into frag-linear fp16 of (1024*c) ----------
// slot g in [0,16384): mt=g>>9, s=(g>>6)&7, l=g&63
// value j: C[mt*32+(l&31)][s*16+(l>>5)*8+j]
__global__ __launch_bounds__(256) void vq_pack(const float* __restrict__ C,
                                               uint4* __restrict__ PH) {
  int g = blockIdx.x * 256 + threadIdx.x;   // grid 64x256
  int mt = g >> 9, s = (g >> 6) & 7, l = g & 63;
  int cw = mt * 32 + (l & 31);
  int k0 = s * 16 + (l >> 5) * 8;
  const float* src = C + (size_t)cw * DIM + k0;
  float4 x0 = *(const float4*)src;
  float4 x1 = *(const float4*)(src + 4);
  unsigned h[8];
  {
    float v[8] = {x0.x, x0.y, x0.z, x0.w, x1.x, x1.y, x1.z, x1.w};
#pragma unroll
    for (int j = 0; j < 8; ++j) { HU u; u.f = (_Float16)(CSCALE * v[j]); h[j] = u.u; }
  }
  PH[g] = make_uint4(h[0] | (h[1] << 16), h[2] | (h[3] << 16),
                     h[4] | (h[5] << 16), h[6] | (h[7] << 16));
}

// ---------- main: 64-row blocks, full sweep, deferred fold, in-block gather ----
__global__ __launch_bounds__(128, 2) void vq_main5(const float* __restrict__ E,
                                                   const float* __restrict__ C,
                                                   float* __restrict__ wsf,
                                                   float* __restrict__ out) {
  __shared__ uint4 SH[2][512];               // 8KB per buf: one 32-cw tile
  __shared__ __align__(16) float CN[1024];
  __shared__ int BI[64];

  const int tid  = threadIdx.x;              // 0..127 (2 waves)
  const int w    = tid >> 6;                 // wave 0..1
  const int l    = tid & 63;
  const int half = l >> 5;
  const int rr   = l & 31;
  const int row0 = blockIdx.x * 64;

  const uint4* PHg = (const uint4*)((const char*)wsf + WS_PH_B);

  // ---- issue async stage of tile 0 + CN (overlaps E load/split below) ----
  {
    const uint4* sh = PHg + tid;
    gload16(sh,       &SH[0][0] + tid);
    gload16(sh + 128, &SH[0][0] + tid + 128);
    gload16(sh + 256, &SH[0][0] + tid + 256);
    gload16(sh + 384, &SH[0][0] + tid + 384);
    const uint4* cn = ((const uint4*)(wsf + WS_CNORM_F)) + tid;
    gload16(cn,       ((uint4*)CN) + tid);
    gload16(cn + 128, ((uint4*)CN) + tid + 128);
  }

  // ---- load this wave's 32 rows into register B-frags, fp16 hi/lo split ----
  // lane (rr,half) covers dims {s*16 + half*8 .. +7} for s=0..7  (64 floats)
  half8 beh[8], bel[8];
  float s2 = 0.f;
  const float* erow = E + (size_t)(row0 + w * 32 + rr) * DIM + half * 8;
#pragma unroll
  for (int s = 0; s < 8; ++s) {
    float4 x0 = *(const float4*)(erow + s * 16);
    float4 x1 = *(const float4*)(erow + s * 16 + 4);
    float v[8] = {x0.x, x0.y, x0.z, x0.w, x1.x, x1.y, x1.z, x1.w};
#pragma unroll
    for (int j = 0; j < 8; ++j) {
      float y = v[j];
      s2 = fmaf(y, y, s2);
      float t = -2.f * y;
      _Float16 hh = (_Float16)t;
      beh[s][j] = hh;
      bel[s][j] = (_Float16)(t - (float)hh);
    }
  }

  asm volatile("s_waitcnt vmcnt(0)" ::: "memory");
  __syncthreads();

  unsigned best = 0xFFFFFFFFu, second = 0xFFFFFFFFu;
  float sc[16];
  int tprev = 0;

#define STAGE_TILE(tn)                                                     \
  {                                                                        \
    const uint4* sh_ = PHg + (size_t)(tn) * 512 + tid;                     \
    uint4* dh_ = &SH[(tn) & 1][0];                                         \
    gload16(sh_,       dh_ + tid);                                         \
    gload16(sh_ + 128, dh_ + tid + 128);                                   \
    gload16(sh_ + 256, dh_ + tid + 256);                                   \
    gload16(sh_ + 384, dh_ + tid + 384);                                   \
  }

#define COMPUTE_TILE(tt, A0, A1)                                           \
  _Pragma("unroll")                                                        \
  for (int s = 0; s < 8; s += 2) {                                         \
    U4H8 h0, h1;                                                           \
    h0.u = SH[(tt) & 1][s * 64 + l];                                       \
    h1.u = SH[(tt) & 1][(s + 1) * 64 + l];                                 \
    A0 = __builtin_amdgcn_mfma_f32_32x32x16_f16(h0.h, beh[s],     A0, 0, 0, 0); \
    A1 = __builtin_amdgcn_mfma_f32_32x32x16_f16(h1.h, beh[s + 1], A1, 0, 0, 0); \
    A0 = __builtin_amdgcn_mfma_f32_32x32x16_f16(h0.h, bel[s],     A0, 0, 0, 0); \
    A1 = __builtin_amdgcn_mfma_f32_32x32x16_f16(h1.h, bel[s + 1], A1, 0, 0, 0); \
  }

#define FOLD_PREV()                                                        \
  {                                                                        \
    const unsigned cwb_ = (unsigned)(tprev * 32 + half * 4);               \
    _Pragma("unroll")                                                      \
    for (int q = 0; q < 4; ++q) {                                          \
      F4A a_; a_.v = *(const float4*)&CN[tprev * 32 + q * 8 + half * 4];   \
      _Pragma("unroll")                                                    \
      for (int i = 0; i < 4; ++i) {                                        \
        float scv_ = fmaf(sc[q * 4 + i], CDESCALE, a_.f[i]);               \
        unsigned u_ = __float_as_uint(scv_);                               \
        u_ ^= ((unsigned)(((int)u_) >> 31)) | 0x80000000u;                 \
        u_ = (u_ & 0xFFFFFC00u) | (cwb_ + (unsigned)(q * 8 + i));          \
        unsigned nb_ = umn(best, u_);                                      \
        second = umn(second, umx(best, u_));                               \
        best = nb_;                                                        \
      }                                                                    \
    }                                                                      \
  }

  // ---- tile 0 (no fold yet) ----
  {
    STAGE_TILE(1);
    float16v acc0 = {0,0,0,0,0,0,0,0,0,0,0,0,0,0,0,0};
    float16v acc1 = {0,0,0,0,0,0,0,0,0,0,0,0,0,0,0,0};
    COMPUTE_TILE(0, acc0, acc1);
#pragma unroll
    for (int r = 0; r < 16; ++r) sc[r] = acc0[r] + acc1[r];
    tprev = 0;
    asm volatile("s_waitcnt vmcnt(0)" ::: "memory");
    __syncthreads();
  }

  // ---- tiles 1..31: compute t, fold t-1 in the MFMA shadow ----
  for (int t = 1; t < 32; ++t) {
    if (t < 31) STAGE_TILE(t + 1);
    float16v acc0 = {0,0,0,0,0,0,0,0,0,0,0,0,0,0,0,0};
    float16v acc1 = {0,0,0,0,0,0,0,0,0,0,0,0,0,0,0,0};
    COMPUTE_TILE(t, acc0, acc1);
    FOLD_PREV();
#pragma unroll
    for (int r = 0; r < 16; ++r) sc[r] = acc0[r] + acc1[r];
    tprev = t;
    asm volatile("s_waitcnt vmcnt(0)" ::: "memory");
    __syncthreads();
  }
  FOLD_PREV();

  // ---- merge halves (lane l <-> l+32 hold same row, disjoint cw subsets) ----
  unsigned ob = (unsigned)__shfl_xor((int)best, 32, 64);
  unsigned os = (unsigned)__shfl_xor((int)second, 32, 64);
  unsigned ns = umn(umn(second, os), umx(best, ob));
  unsigned nb = umn(best, ob);
  float en = s2 + __shfl_xor(s2, 32, 64);

  if (half == 0) {
    const int r = w * 32 + rr;
    int   bi = (int)(nb & 1023u);
    float bv = unmap_score(nb & 0xFFFFFC00u);
    float sv = unmap_score(ns & 0xFFFFFC00u);
    out[row0 + r] = (float)bi;
    BI[r] = bi;
    if (sv - bv < MARGIN) {
      unsigned idx = atomicAdd((unsigned*)wsf + 1, 1u);
      if (idx < FLAGCAP) ((int*)((char*)wsf + WS_LIST_B))[idx] = row0 + r;
    }
    float term = en + bv;
#pragma unroll
    for (int off = 16; off > 0; off >>= 1) term += __shfl_down(term, off);
    if (rr == 0) atomicAdd(wsf, term);
  }
  __syncthreads();

  // ---- gather quantized_st ----
  const float4* C4   = (const float4*)C;
  float4*       out4 = (float4*)out;
#pragma unroll
  for (int it = 0; it < 16; ++it) {
    int flat = it * 128 + tid;
    int r = flat >> 5, d4 = flat & 31;
    out4[(NROWS / 4) + (size_t)(row0 + r) * DV + d4] = C4[(size_t)BI[r] * DV + d4];
  }
#undef STAGE_TILE
#undef COMPUTE_TILE
#undef FOLD_PREV
}

// ---------- exact fp32 rescan of flagged rows (2 rows per sweep) ----------
__global__ __launch_bounds__(256) void vq_fix(const float* __restrict__ E,
                                              const float* __restrict__ C,
                                              float* __restrict__ wsf,
                                              float* __restrict__ out) {
  __shared__ float4 eL0[32], eL1[32];
  __shared__ float  sv0[256], sv1[256];
  __shared__ int    si0[256], si1[256];
  __shared__ int    RESi[2];
  const int tid = threadIdx.x;
  const int* list = (const int*)((const char*)wsf + WS_LIST_B);
  int nf = (int)((const unsigned*)wsf)[1];
  if (nf > FLAGCAP) nf = FLAGCAP;
  const float4* E4 = (const float4*)E;
  const float4* C4 = (const float4*)C;
  const float*  cn = wsf + WS_CNORM_F;
  float4* out4 = (float4*)out;

  for (int pair = blockIdx.x; pair * 2 < nf; pair += gridDim.x) {
    const int r0 = list[pair * 2];
    const int r1 = (pair * 2 + 1 < nf) ? list[pair * 2 + 1] : r0;
    if (tid < 32) eL0[tid] = E4[(size_t)r0 * DV + tid];
    else if (tid < 64) eL1[tid - 32] = E4[(size_t)r1 * DV + (tid - 32)];
    __syncthreads();
    float bv0 = 3.0e38f, bv1 = 3.0e38f; int bi0 = 0, bi1 = 0;
#pragma unroll
    for (int j = 0; j < 4; ++j) {
      int k = j * 256 + tid;
      float d0 = 0.f, d1 = 0.f;
#pragma unroll 8
      for (int d4 = 0; d4 < 32; ++d4) {
        float4 c = C4[(size_t)k * DV + d4];
        float4 e0 = eL0[d4], e1 = eL1[d4];
        d0 = fmaf(c.x, e0.x, d0); d0 = fmaf(c.y, e0.y, d0);
        d0 = fmaf(c.z, e0.z, d0); d0 = fmaf(c.w, e0.w, d0);
        d1 = fmaf(c.x, e1.x, d1); d1 = fmaf(c.y, e1.y, d1);
        d1 = fmaf(c.z, e1.z, d1); d1 = fmaf(c.w, e1.w, d1);
      }
      float s0 = fmaf(-2.f, d0, cn[k]);
      float s1 = fmaf(-2.f, d1, cn[k]);
      if (s0 < bv0 || (s0 == bv0 && k < bi0)) { bv0 = s0; bi0 = k; }
      if (s1 < bv1 || (s1 == bv1 && k < bi1)) { bv1 = s1; bi1 = k; }
    }
    sv0[tid] = bv0; si0[tid] = bi0; sv1[tid] = bv1; si1[tid] = bi1;
    __syncthreads();
    if (tid < 64) {
      float v0 = sv0[tid]; int i0 = si0[tid];
      float v1 = sv1[tid]; int i1 = si1[tid];
#pragma unroll
      for (int q = 1; q < 4; ++q) {
        float w0 = sv0[tid + q * 64]; int j0 = si0[tid + q * 64];
        float w1 = sv1[tid + q * 64]; int j1 = si1[tid + q * 64];
        if (w0 < v0 || (w0 == v0 && j0 < i0)) { v0 = w0; i0 = j0; }
        if (w1 < v1 || (w1 == v1 && j1 < i1)) { v1 = w1; i1 = j1; }
      }
#pragma unroll
      for (int off = 32; off > 0; off >>= 1) {
        float w0 = __shfl_down(v0, off); int j0 = __shfl_down(i0, off);
        float w1 = __shfl_down(v1, off); int j1 = __shfl_down(i1, off);
        if (w0 < v0 || (w0 == v0 && j0 < i0)) { v0 = w0; i0 = j0; }
        if (w1 < v1 || (w1 == v1 && j1 < i1)) { v1 = w1; i1 = j1; }
      }
      if (tid == 0) {
        RESi[0] = i0; RESi[1] = i1;
        out[r0] = (float)i0; out[r1] = (float)i1;
      }
    }
    __syncthreads();
    if (tid < 32) out4[(NROWS / 4) + (size_t)r0 * DV + tid] = C4[(size_t)RESi[0] * DV + tid];
    else if (tid < 64) out4[(NROWS / 4) + (size_t)r1 * DV + (tid - 32)] = C4[(size_t)RESi[1] * DV + (tid - 32)];
    __syncthreads();
  }
}

// ---------- final scalars ----------
__global__ void vq_final(const float* __restrict__ wsf, float* __restrict__ out) {
  if (threadIdx.x == 0 && blockIdx.x == 0) {
    float mse = wsf[0] / MSE_DENOM;
    out[NROWS + NROWS * DIM + 0] = 1.25f * mse;
    out[NROWS + NROWS * DIM + 1] = mse;
    out[NROWS + NROWS * DIM + 2] = mse;
  }
}

// ================= fallback (round-1 fp32 path, used if ws too small) ==========
__global__ __launch_bounds__(256) void vq_prep_fb(const float* __restrict__ C,
                                                  float* __restrict__ ws) {
  int k = blockIdx.x * 256 + threadIdx.x;
  if (k == 0) ws[0] = 0.0f;
  const float4* c4 = (const float4*)C + (size_t)k * DV;
  float s = 0.f;
#pragma unroll 8
  for (int i = 0; i < DV; ++i) {
    float4 v = c4[i];
    s = fmaf(v.x, v.x, s); s = fmaf(v.y, v.y, s);
    s = fmaf(v.z, v.z, s); s = fmaf(v.w, v.w, s);
  }
  ws[64 + k] = s;
}

__global__ __launch_bounds__(256) void vq_main_fb(const float* __restrict__ E,
                                                  const float* __restrict__ C,
                                                  const float* __restrict__ cnorm,
                                                  float* __restrict__ out,
                                                  float* __restrict__ lossacc) {
  __shared__ float smem[16384];
  float4* EsV = (float4*)smem;
  float4* CsV = (float4*)(smem + 8192);
  const int tid  = threadIdx.x;
  const int row0 = blockIdx.x * 64;
#pragma unroll
  for (int i = 0; i < 8; ++i) {
    int flat = i * 256 + tid;
    int r = flat >> 5, d4 = flat & 31;
    EsV[r * 32 + (d4 ^ (r & 31))] = ((const float4*)E)[(size_t)(row0 + r) * DV + d4];
  }
  const int tx = tid & 15, ty = tid >> 4;
  int rbase[4], rmask[4];
#pragma unroll
  for (int i = 0; i < 4; ++i) { int r = i * 16 + ty; rbase[i] = r * 32; rmask[i] = r & 31; }
  float bestv[4]; int besti[4];
#pragma unroll
  for (int i = 0; i < 4; ++i) { bestv[i] = 3.0e38f; besti[i] = 0; }
  for (int ch = 0; ch < 16; ++ch) {
    const int k0 = ch * 64;
    __syncthreads();
#pragma unroll
    for (int i = 0; i < 8; ++i) {
      int flat = i * 256 + tid;
      int k = flat >> 5, d4 = flat & 31;
      CsV[k * 32 + (d4 ^ (k & 31))] = ((const float4*)C)[(size_t)(k0 + k) * DV + d4];
    }
    __syncthreads();
    float acc[4][4] = {};
#pragma unroll 8
    for (int d4 = 0; d4 < DV; ++d4) {
      float4 a[4], b[4];
#pragma unroll
      for (int i = 0; i < 4; ++i) a[i] = EsV[rbase[i] + (d4 ^ rmask[i])];
#pragma unroll
      for (int j = 0; j < 4; ++j) { int k = j * 16 + tx; b[j] = CsV[k * 32 + (d4 ^ (k & 31))]; }
#pragma unroll
      for (int i = 0; i < 4; ++i)
#pragma unroll
        for (int j = 0; j < 4; ++j) {
          acc[i][j] = fmaf(a[i].x, b[j].x, acc[i][j]);
          acc[i][j] = fmaf(a[i].y, b[j].y, acc[i][j]);
          acc[i][j] = fmaf(a[i].z, b[j].z, acc[i][j]);
          acc[i][j] = fmaf(a[i].w, b[j].w, acc[i][j]);
        }
    }
#pragma unroll
    for (int j = 0; j < 4; ++j) {
      int kg = k0 + j * 16 + tx;
      float cnv = cnorm[kg];
#pragma unroll
      for (int i = 0; i < 4; ++i) {
        float s = fmaf(-2.0f, acc[i][j], cnv);
        if (s < bestv[i] || (s == bestv[i] && kg < besti[i])) { bestv[i] = s; besti[i] = kg; }
      }
    }
  }
  float* Rv = smem + 8192;
  int*   Ri = (int*)(smem + 9216);
  int*   BIf = (int*)(smem + 10240);
  __syncthreads();
#pragma unroll
  for (int i = 0; i < 4; ++i) {
    int r = i * 16 + ty;
    Rv[r * 16 + tx] = bestv[i];
    Ri[r * 16 + tx] = besti[i];
  }
  __syncthreads();
  if (tid < 64) {
    const int r = tid;
    float bv = Rv[r * 16]; int bi = Ri[r * 16];
#pragma unroll
    for (int t = 1; t < 16; ++t) {
      float v = Rv[r * 16 + t]; int ii = Ri[r * 16 + t];
      if (v < bv || (v == bv && ii < bi)) { bv = v; bi = ii; }
    }
    float en = 0.f;
#pragma unroll 8
    for (int d4 = 0; d4 < DV; ++d4) {
      float4 v = EsV[r * 32 + (d4 ^ (r & 31))];
      en = fmaf(v.x, v.x, en); en = fmaf(v.y, v.y, en);
      en = fmaf(v.z, v.z, en); en = fmaf(v.w, v.w, en);
    }
    out[row0 + r] = (float)bi;
    BIf[r] = bi;
    float blocksum = en + bv;
#pragma unroll
    for (int off = 32; off > 0; off >>= 1) blocksum += __shfl_down(blocksum, off);
    if (tid == 0) atomicAdd(lossacc, blocksum);
  }
  __syncthreads();
  const float4* C4   = (const float4*)C;
  float4*       out4 = (float4*)out;
  for (int flat = tid; flat < 64 * DV; flat += 256) {
    int r = flat >> 5, d4 = flat & 31;
    out4[(NROWS / 4) + (size_t)(row0 + r) * DV + d4] = C4[(size_t)BIf[r] * DV + d4];
  }
}

__global__ void vq_final_fb(const float* __restrict__ ws, float* __restrict__ out) {
  if (threadIdx.x == 0 && blockIdx.x == 0) {
    float mse = ws[0] / MSE_DENOM;
    out[NROWS + NROWS * DIM + 0] = 1.25f * mse;
    out[NROWS + NROWS * DIM + 1] = mse;
    out[NROWS + NROWS * DIM + 2] = mse;
  }
}

extern "C" void kernel_launch(void* const* d_in, const int* in_sizes, int n_in,
                              void* d_out, int out_size, void* d_ws, size_t ws_size,
                              hipStream_t stream) {
  const float* E = (const float*)d_in[0];
  const float* C = (const float*)d_in[1];
  float* out = (float*)d_out;
  float* wsf = (float*)d_ws;

  if (ws_size >= (size_t)WS_NEEDED) {
    uint4* PH = (uint4*)((char*)d_ws + WS_PH_B);
    vq_prep0<<<4, 256, 0, stream>>>(C, wsf);
    vq_pack<<<64, 256, 0, stream>>>(C, PH);
    vq_main5<<<NROWS / 64, 128, 0, stream>>>(E, C, wsf, out);
    vq_fix<<<512, 256, 0, stream>>>(E, C, wsf, out);
    vq_final<<<1, 64, 0, stream>>>(wsf, out);
  } else {
    vq_prep_fb<<<4, 256, 0, stream>>>(C, wsf);
    vq_main_fb<<<NROWS / 64, 256, 0, stream>>>(E, C, wsf + 64, out, wsf);
    vq_final_fb<<<1, 64, 0, stream>>>(wsf, out);
  }
}

// Round 4
// 166.833 us; speedup vs baseline: 1.1272x; 1.0010x over previous
//
#include <hip/hip_runtime.h>

// VectorQuantizer, single-term fp16 MFMA, register-resident E / LDS-streamed codebook.
// scores = -2*E@C^T + ||c||^2; argmin_k; gather; mse losses.
//   eh = fp16(-2e), ch = fp16(1024c); acc = eh@ch (fp32 MFMA accum)
//   score = acc * 2^-10 + ||c||^2 ; dropped-term err sigma ~3e-6 << MARGIN=3e-5
// Block = 128 threads (2 waves) x 64 rows; grid 1024 -> 4 blocks/CU.
// Per step: TWO 32-cw tiles (16KB), dbuf'd via global_load_lds staged one pair
// ahead; 4 independent MFMA chains/wave; fold inline. 16 steps, 16 barriers.
// Rows whose top-2 gap < MARGIN get an exact fp32 rescan (vq_fix, 4 rows/sweep).
// Output: [0,N) idx as float | [N,N+N*D) quantized | +0,1,2 = vq,embed,commit.

#define NROWS 65536
#define KCB   1024
#define DIM   128
#define DV    32
#define MSE_DENOM 8388608.0f
#define MARGIN 3.0e-5f
#define FLAGCAP 16384
#define CSCALE   1024.0f
#define CDESCALE 0.0009765625f

// ws byte layout
#define WS_CNORM_F 256      // float index: cnorm[1024] at byte 1024
#define WS_LIST_B  8192     // 16384 ints
#define WS_PH_B    73728    // 262144 B packed codebook frags (fp16)
#define WS_NEEDED  335872

typedef __attribute__((ext_vector_type(16))) float float16v;
typedef _Float16 half8 __attribute__((ext_vector_type(8)));
union U4H8 { uint4 u; half8 h; };
union F4A  { float4 v; float f[4]; };
union HU   { _Float16 f; unsigned short u; };

__device__ __forceinline__ unsigned umn(unsigned a, unsigned b) { return a < b ? a : b; }
__device__ __forceinline__ unsigned umx(unsigned a, unsigned b) { return a > b ? a : b; }
__device__ __forceinline__ float unmap_score(unsigned up) {
  return (up & 0x80000000u) ? __uint_as_float(up ^ 0x80000000u) : __uint_as_float(~up);
}
__device__ __forceinline__ void gload16(const void* g, void* s) {
  __builtin_amdgcn_global_load_lds((const __attribute__((address_space(1))) unsigned int*)g,
                                   (__attribute__((address_space(3))) unsigned int*)s,
                                   16, 0, 0);
}

// ---------- prep0: cnorm + zero loss/nflag ----------
__global__ __launch_bounds__(64) void vq_prep0(const float* __restrict__ C,
                                               float* __restrict__ wsf) {
  int k = blockIdx.x * 64 + threadIdx.x;    // grid 16x64 == 1024
  if (k == 0) { wsf[0] = 0.0f; ((unsigned*)wsf)[1] = 0u; }
  const float4* c4 = (const float4*)C + (size_t)k * DV;
  float s = 0.f;
#pragma unroll 8
  for (int i = 0; i < DV; ++i) {
    float4 v = c4[i];
    s = fmaf(v.x, v.x, s); s = fmaf(v.y, v.y, s);
    s = fmaf(v.z, v.z, s); s = fmaf(v.w, v.w, s);
  }
  wsf[WS_CNORM_F + k] = s;
}

// ---------- pack codebook into frag-linear fp16 of (1024*c) ----------
// slot g in [0,16384): mt=g>>9, s=(g>>6)&7, l=g&63
// value j: C[mt*32+(l&31)][s*16+(l>>5)*8+j]
__global__ __launch_bounds__(256) void vq_pack(const float* __restrict__ C,
                                               uint4* __restrict__ PH) {
  int g = blockIdx.x * 256 + threadIdx.x;   // grid 64x256
  int mt = g >> 9, s = (g >> 6) & 7, l = g & 63;
  int cw = mt * 32 + (l & 31);
  int k0 = s * 16 + (l >> 5) * 8;
  const float* src = C + (size_t)cw * DIM + k0;
  float4 x0 = *(const float4*)src;
  float4 x1 = *(const float4*)(src + 4);
  unsigned h[8];
  {
    float v[8] = {x0.x, x0.y, x0.z, x0.w, x1.x, x1.y, x1.z, x1.w};
#pragma unroll
    for (int j = 0; j < 8; ++j) { HU u; u.f = (_Float16)(CSCALE * v[j]); h[j] = u.u; }
  }
  PH[g] = make_uint4(h[0] | (h[1] << 16), h[2] | (h[3] << 16),
                     h[4] | (h[5] << 16), h[6] | (h[7] << 16));
}

// ---------- main: 64-row blocks, 2 tiles/step, single-term, in-block gather ----
__global__ __launch_bounds__(128, 2) void vq_main6(const float* __restrict__ E,
                                                   const float* __restrict__ C,
                                                   float* __restrict__ wsf,
                                                   float* __restrict__ out) {
  __shared__ uint4 SH[2][1024];              // 16KB per buf: one 2-tile pair
  __shared__ __align__(16) float CN[1024];
  __shared__ int BI[64];

  const int tid  = threadIdx.x;              // 0..127 (2 waves)
  const int w    = tid >> 6;                 // wave 0..1
  const int l    = tid & 63;
  const int half = l >> 5;
  const int rr   = l & 31;
  const int row0 = blockIdx.x * 64;

  const uint4* PHg = (const uint4*)((const char*)wsf + WS_PH_B);

  // ---- issue async stage of pair 0 (tiles 0,1) + CN ----
  {
    const uint4* sh = PHg + tid;
#pragma unroll
    for (int k = 0; k < 8; ++k)
      gload16(sh + k * 128, &SH[0][0] + tid + k * 128);
    const uint4* cn = ((const uint4*)(wsf + WS_CNORM_F)) + tid;
    gload16(cn,       ((uint4*)CN) + tid);
    gload16(cn + 128, ((uint4*)CN) + tid + 128);
  }

  // ---- load this wave's 32 rows into register B-frags (single fp16 term) ----
  // lane (rr,half) covers dims {s*16 + half*8 .. +7} for s=0..7  (64 floats)
  half8 beh[8];
  float s2 = 0.f;
  const float* erow = E + (size_t)(row0 + w * 32 + rr) * DIM + half * 8;
#pragma unroll
  for (int s = 0; s < 8; ++s) {
    float4 x0 = *(const float4*)(erow + s * 16);
    float4 x1 = *(const float4*)(erow + s * 16 + 4);
    float v[8] = {x0.x, x0.y, x0.z, x0.w, x1.x, x1.y, x1.z, x1.w};
#pragma unroll
    for (int j = 0; j < 8; ++j) {
      float y = v[j];
      s2 = fmaf(y, y, s2);
      beh[s][j] = (_Float16)(-2.f * y);
    }
  }

  asm volatile("s_waitcnt vmcnt(0)" ::: "memory");
  __syncthreads();

  unsigned best = 0xFFFFFFFFu, second = 0xFFFFFFFFu;

  for (int t = 0; t < 16; ++t) {
    const int b = t & 1;
    // stage next pair (async, lands before end-of-step drain)
    if (t < 15) {
      const uint4* sh = PHg + (size_t)(t + 1) * 1024 + tid;
      uint4* dh = &SH[b ^ 1][0];
#pragma unroll
      for (int k = 0; k < 8; ++k)
        gload16(sh + k * 128, dh + tid + k * 128);
    }

    // 4 independent MFMA chains: 2 tiles x 2 k-split accumulators
    float16v a0 = {0,0,0,0,0,0,0,0,0,0,0,0,0,0,0,0};
    float16v a1 = {0,0,0,0,0,0,0,0,0,0,0,0,0,0,0,0};
    float16v b0 = {0,0,0,0,0,0,0,0,0,0,0,0,0,0,0,0};
    float16v b1 = {0,0,0,0,0,0,0,0,0,0,0,0,0,0,0,0};
#pragma unroll
    for (int s = 0; s < 8; s += 2) {
      U4H8 hA0, hA1, hB0, hB1;
      hA0.u = SH[b][s * 64 + l];
      hA1.u = SH[b][(s + 1) * 64 + l];
      hB0.u = SH[b][512 + s * 64 + l];
      hB1.u = SH[b][512 + (s + 1) * 64 + l];
      a0 = __builtin_amdgcn_mfma_f32_32x32x16_f16(hA0.h, beh[s],     a0, 0, 0, 0);
      a1 = __builtin_amdgcn_mfma_f32_32x32x16_f16(hA1.h, beh[s + 1], a1, 0, 0, 0);
      b0 = __builtin_amdgcn_mfma_f32_32x32x16_f16(hB0.h, beh[s],     b0, 0, 0, 0);
      b1 = __builtin_amdgcn_mfma_f32_32x32x16_f16(hB1.h, beh[s + 1], b1, 0, 0, 0);
    }

    // fold both tiles (lane's row = rr; cw = tg*32 + half*4 + q*8 + i)
#pragma unroll
    for (int tt = 0; tt < 2; ++tt) {
      const int tg = t * 2 + tt;
      const unsigned cwb = (unsigned)(tg * 32 + half * 4);
#pragma unroll
      for (int q = 0; q < 4; ++q) {
        F4A a; a.v = *(const float4*)&CN[tg * 32 + q * 8 + half * 4];
#pragma unroll
        for (int i = 0; i < 4; ++i) {
          float acc = tt ? (b0[q * 4 + i] + b1[q * 4 + i])
                         : (a0[q * 4 + i] + a1[q * 4 + i]);
          float sc = fmaf(acc, CDESCALE, a.f[i]);
          unsigned u = __float_as_uint(sc);
          u ^= ((unsigned)(((int)u) >> 31)) | 0x80000000u;
          u = (u & 0xFFFFFC00u) | (cwb + (unsigned)(q * 8 + i));
          unsigned nb = umn(best, u);
          second = umn(second, umx(best, u));
          best = nb;
        }
      }
    }

    asm volatile("s_waitcnt vmcnt(0)" ::: "memory");
    __syncthreads();
  }

  // ---- merge halves (lane l <-> l+32 hold same row, disjoint cw subsets) ----
  unsigned ob = (unsigned)__shfl_xor((int)best, 32, 64);
  unsigned os = (unsigned)__shfl_xor((int)second, 32, 64);
  unsigned ns = umn(umn(second, os), umx(best, ob));
  unsigned nb = umn(best, ob);
  float en = s2 + __shfl_xor(s2, 32, 64);

  if (half == 0) {
    const int r = w * 32 + rr;
    int   bi = (int)(nb & 1023u);
    float bv = unmap_score(nb & 0xFFFFFC00u);
    float sv = unmap_score(ns & 0xFFFFFC00u);
    out[row0 + r] = (float)bi;
    BI[r] = bi;
    if (sv - bv < MARGIN) {
      unsigned idx = atomicAdd((unsigned*)wsf + 1, 1u);
      if (idx < FLAGCAP) ((int*)((char*)wsf + WS_LIST_B))[idx] = row0 + r;
    }
    float term = en + bv;
#pragma unroll
    for (int off = 16; off > 0; off >>= 1) term += __shfl_down(term, off);
    if (rr == 0) atomicAdd(wsf, term);
  }
  __syncthreads();

  // ---- gather quantized_st ----
  const float4* C4   = (const float4*)C;
  float4*       out4 = (float4*)out;
#pragma unroll
  for (int it = 0; it < 16; ++it) {
    int flat = it * 128 + tid;
    int r = flat >> 5, d4 = flat & 31;
    out4[(NROWS / 4) + (size_t)(row0 + r) * DV + d4] = C4[(size_t)BI[r] * DV + d4];
  }
}

// ---------- exact fp32 rescan of flagged rows (4 rows per sweep) ----------
__global__ __launch_bounds__(256) void vq_fix(const float* __restrict__ E,
                                              const float* __restrict__ C,
                                              float* __restrict__ wsf,
                                              float* __restrict__ out) {
  __shared__ float4 eL[4][32];
  __shared__ float  RV[4][4];
  __shared__ int    RI[4][4];
  __shared__ int    RESi[4];
  const int tid = threadIdx.x;
  const int wv  = tid >> 6;
  const int ln  = tid & 63;
  const int* list = (const int*)((const char*)wsf + WS_LIST_B);
  int nf = (int)((const unsigned*)wsf)[1];
  if (nf > FLAGCAP) nf = FLAGCAP;
  const float4* E4 = (const float4*)E;
  const float4* C4 = (const float4*)C;
  const float*  cn = wsf + WS_CNORM_F;
  float4* out4 = (float4*)out;

  for (int g = blockIdx.x; g * 4 < nf; g += gridDim.x) {
    const int base = g * 4;
    if (tid < 128) {
      int r = tid >> 5, d4 = tid & 31;
      int R = (base + r < nf) ? list[base + r] : list[base];
      eL[r][d4] = E4[(size_t)R * DV + d4];
    }
    __syncthreads();
    float bv[4] = {3.0e38f, 3.0e38f, 3.0e38f, 3.0e38f};
    int   bi[4] = {0, 0, 0, 0};
#pragma unroll
    for (int j = 0; j < 4; ++j) {
      int k = j * 256 + tid;
      float d0 = 0.f, d1 = 0.f, d2 = 0.f, d3 = 0.f;
#pragma unroll 4
      for (int d4 = 0; d4 < 32; ++d4) {
        float4 c = C4[(size_t)k * DV + d4];
        float4 e0 = eL[0][d4], e1 = eL[1][d4], e2 = eL[2][d4], e3 = eL[3][d4];
        d0 = fmaf(c.x, e0.x, d0); d0 = fmaf(c.y, e0.y, d0);
        d0 = fmaf(c.z, e0.z, d0); d0 = fmaf(c.w, e0.w, d0);
        d1 = fmaf(c.x, e1.x, d1); d1 = fmaf(c.y, e1.y, d1);
        d1 = fmaf(c.z, e1.z, d1); d1 = fmaf(c.w, e1.w, d1);
        d2 = fmaf(c.x, e2.x, d2); d2 = fmaf(c.y, e2.y, d2);
        d2 = fmaf(c.z, e2.z, d2); d2 = fmaf(c.w, e2.w, d2);
        d3 = fmaf(c.x, e3.x, d3); d3 = fmaf(c.y, e3.y, d3);
        d3 = fmaf(c.z, e3.z, d3); d3 = fmaf(c.w, e3.w, d3);
      }
      float cnk = cn[k];
      float s0 = fmaf(-2.f, d0, cnk);
      float s1 = fmaf(-2.f, d1, cnk);
      float s2 = fmaf(-2.f, d2, cnk);
      float s3 = fmaf(-2.f, d3, cnk);
      if (s0 < bv[0] || (s0 == bv[0] && k < bi[0])) { bv[0] = s0; bi[0] = k; }
      if (s1 < bv[1] || (s1 == bv[1] && k < bi[1])) { bv[1] = s1; bi[1] = k; }
      if (s2 < bv[2] || (s2 == bv[2] && k < bi[2])) { bv[2] = s2; bi[2] = k; }
      if (s3 < bv[3] || (s3 == bv[3] && k < bi[3])) { bv[3] = s3; bi[3] = k; }
    }
#pragma unroll
    for (int off = 32; off > 0; off >>= 1) {
#pragma unroll
      for (int r = 0; r < 4; ++r) {
        float wv_ = __shfl_down(bv[r], off);
        int   ji  = __shfl_down(bi[r], off);
        if (wv_ < bv[r] || (wv_ == bv[r] && ji < bi[r])) { bv[r] = wv_; bi[r] = ji; }
      }
    }
    if (ln == 0) {
#pragma unroll
      for (int r = 0; r < 4; ++r) { RV[wv][r] = bv[r]; RI[wv][r] = bi[r]; }
    }
    __syncthreads();
    if (tid < 4) {
      float v = RV[0][tid]; int i = RI[0][tid];
#pragma unroll
      for (int q = 1; q < 4; ++q) {
        float vv = RV[q][tid]; int ii = RI[q][tid];
        if (vv < v || (vv == v && ii < i)) { v = vv; i = ii; }
      }
      RESi[tid] = i;
      if (base + tid < nf) out[list[base + tid]] = (float)i;
    }
    __syncthreads();
    if (tid < 128) {
      int r = tid >> 5, d4 = tid & 31;
      if (base + r < nf) {
        int R = list[base + r];
        out4[(NROWS / 4) + (size_t)R * DV + d4] = C4[(size_t)RESi[r] * DV + d4];
      }
    }
    __syncthreads();
  }
}

// ---------- final scalars ----------
__global__ void vq_final(const float* __restrict__ wsf, float* __restrict__ out) {
  if (threadIdx.x == 0 && blockIdx.x == 0) {
    float mse = wsf[0] / MSE_DENOM;
    out[NROWS + NROWS * DIM + 0] = 1.25f * mse;
    out[NROWS + NROWS * DIM + 1] = mse;
    out[NROWS + NROWS * DIM + 2] = mse;
  }
}

// ================= fallback (round-1 fp32 path, used if ws too small) ==========
__global__ __launch_bounds__(256) void vq_prep_fb(const float* __restrict__ C,
                                                  float* __restrict__ ws) {
  int k = blockIdx.x * 256 + threadIdx.x;
  if (k == 0) ws[0] = 0.0f;
  const float4* c4 = (const float4*)C + (size_t)k * DV;
  float s = 0.f;
#pragma unroll 8
  for (int i = 0; i < DV; ++i) {
    float4 v = c4[i];
    s = fmaf(v.x, v.x, s); s = fmaf(v.y, v.y, s);
    s = fmaf(v.z, v.z, s); s = fmaf(v.w, v.w, s);
  }
  ws[64 + k] = s;
}

__global__ __launch_bounds__(256) void vq_main_fb(const float* __restrict__ E,
                                                  const float* __restrict__ C,
                                                  const float* __restrict__ cnorm,
                                                  float* __restrict__ out,
                                                  float* __restrict__ lossacc) {
  __shared__ float smem[16384];
  float4* EsV = (float4*)smem;
  float4* CsV = (float4*)(smem + 8192);
  const int tid  = threadIdx.x;
  const int row0 = blockIdx.x * 64;
#pragma unroll
  for (int i = 0; i < 8; ++i) {
    int flat = i * 256 + tid;
    int r = flat >> 5, d4 = flat & 31;
    EsV[r * 32 + (d4 ^ (r & 31))] = ((const float4*)E)[(size_t)(row0 + r) * DV + d4];
  }
  const int tx = tid & 15, ty = tid >> 4;
  int rbase[4], rmask[4];
#pragma unroll
  for (int i = 0; i < 4; ++i) { int r = i * 16 + ty; rbase[i] = r * 32; rmask[i] = r & 31; }
  float bestv[4]; int besti[4];
#pragma unroll
  for (int i = 0; i < 4; ++i) { bestv[i] = 3.0e38f; besti[i] = 0; }
  for (int ch = 0; ch < 16; ++ch) {
    const int k0 = ch * 64;
    __syncthreads();
#pragma unroll
    for (int i = 0; i < 8; ++i) {
      int flat = i * 256 + tid;
      int k = flat >> 5, d4 = flat & 31;
      CsV[k * 32 + (d4 ^ (k & 31))] = ((const float4*)C)[(size_t)(k0 + k) * DV + d4];
    }
    __syncthreads();
    float acc[4][4] = {};
#pragma unroll 8
    for (int d4 = 0; d4 < DV; ++d4) {
      float4 a[4], b[4];
#pragma unroll
      for (int i = 0; i < 4; ++i) a[i] = EsV[rbase[i] + (d4 ^ rmask[i])];
#pragma unroll
      for (int j = 0; j < 4; ++j) { int k = j * 16 + tx; b[j] = CsV[k * 32 + (d4 ^ (k & 31))]; }
#pragma unroll
      for (int i = 0; i < 4; ++i)
#pragma unroll
        for (int j = 0; j < 4; ++j) {
          acc[i][j] = fmaf(a[i].x, b[j].x, acc[i][j]);
          acc[i][j] = fmaf(a[i].y, b[j].y, acc[i][j]);
          acc[i][j] = fmaf(a[i].z, b[j].z, acc[i][j]);
          acc[i][j] = fmaf(a[i].w, b[j].w, acc[i][j]);
        }
    }
#pragma unroll
    for (int j = 0; j < 4; ++j) {
      int kg = k0 + j * 16 + tx;
      float cnv = cnorm[kg];
#pragma unroll
      for (int i = 0; i < 4; ++i) {
        float s = fmaf(-2.0f, acc[i][j], cnv);
        if (s < bestv[i] || (s == bestv[i] && kg < besti[i])) { bestv[i] = s; besti[i] = kg; }
      }
    }
  }
  float* Rv = smem + 8192;
  int*   Ri = (int*)(smem + 9216);
  int*   BIf = (int*)(smem + 10240);
  __syncthreads();
#pragma unroll
  for (int i = 0; i < 4; ++i) {
    int r = i * 16 + ty;
    Rv[r * 16 + tx] = bestv[i];
    Ri[r * 16 + tx] = besti[i];
  }
  __syncthreads();
  if (tid < 64) {
    const int r = tid;
    float bv = Rv[r * 16]; int bi = Ri[r * 16];
#pragma unroll
    for (int t = 1; t < 16; ++t) {
      float v = Rv[r * 16 + t]; int ii = Ri[r * 16 + t];
      if (v < bv || (v == bv && ii < bi)) { bv = v; bi = ii; }
    }
    float en = 0.f;
#pragma unroll 8
    for (int d4 = 0; d4 < DV; ++d4) {
      float4 v = EsV[r * 32 + (d4 ^ (r & 31))];
      en = fmaf(v.x, v.x, en); en = fmaf(v.y, v.y, en);
      en = fmaf(v.z, v.z, en); en = fmaf(v.w, v.w, en);
    }
    out[row0 + r] = (float)bi;
    BIf[r] = bi;
    float blocksum = en + bv;
#pragma unroll
    for (int off = 32; off > 0; off >>= 1) blocksum += __shfl_down(blocksum, off);
    if (tid == 0) atomicAdd(lossacc, blocksum);
  }
  __syncthreads();
  const float4* C4   = (const float4*)C;
  float4*       out4 = (float4*)out;
  for (int flat = tid; flat < 64 * DV; flat += 256) {
    int r = flat >> 5, d4 = flat & 31;
    out4[(NROWS / 4) + (size_t)(row0 + r) * DV + d4] = C4[(size_t)BIf[r] * DV + d4];
  }
}

__global__ void vq_final_fb(const float* __restrict__ ws, float* __restrict__ out) {
  if (threadIdx.x == 0 && blockIdx.x == 0) {
    float mse = ws[0] / MSE_DENOM;
    out[NROWS + NROWS * DIM + 0] = 1.25f * mse;
    out[NROWS + NROWS * DIM + 1] = mse;
    out[NROWS + NROWS * DIM + 2] = mse;
  }
}

extern "C" void kernel_launch(void* const* d_in, const int* in_sizes, int n_in,
                              void* d_out, int out_size, void* d_ws, size_t ws_size,
                              hipStream_t stream) {
  const float* E = (const float*)d_in[0];
  const float* C = (const float*)d_in[1];
  float* out = (float*)d_out;
  float* wsf = (float*)d_ws;

  if (ws_size >= (size_t)WS_NEEDED) {
    uint4* PH = (uint4*)((char*)d_ws + WS_PH_B);
    vq_prep0<<<16, 64, 0, stream>>>(C, wsf);
    vq_pack<<<64, 256, 0, stream>>>(C, PH);
    vq_main6<<<NROWS / 64, 128, 0, stream>>>(E, C, wsf, out);
    vq_fix<<<256, 256, 0, stream>>>(E, C, wsf, out);
    vq_final<<<1, 64, 0, stream>>>(wsf, out);
  } else {
    vq_prep_fb<<<4, 256, 0, stream>>>(C, wsf);
    vq_main_fb<<<NROWS / 64, 256, 0, stream>>>(E, C, wsf + 64, out, wsf);
    vq_final_fb<<<1, 64, 0, stream>>>(wsf, out);
  }
}